// Round 1
// baseline (205.720 us; speedup 1.0000x reference)
//
#include <hip/hip_runtime.h>

// LSTM fused: B=4096, T=200, F=64, H=16, O=1
// One wave (64 lanes) per batch element; lane j owns gate j (4H=64).
// Gate order (PyTorch): i=[0,16), f=[16,32), g=[32,48), o=[48,64).

#define Bsz 4096
#define Tn  200
#define Fn  64
#define Hn  16

__global__ __launch_bounds__(256) void lstm_fused(
    const float* __restrict__ x,     // [B, T, F]
    const float* __restrict__ Wih,   // [4H, F] = [64, 64]
    const float* __restrict__ Whh,   // [4H, H] = [64, 16]
    const float* __restrict__ bih,   // [64]
    const float* __restrict__ bhh,   // [64]
    const float* __restrict__ Wout,  // [1, 16]
    const float* __restrict__ bout,  // [1]
    float* __restrict__ out)         // [B, 1]
{
    const int lane = threadIdx.x & 63;
    const int wid  = threadIdx.x >> 6;
    // force wave-uniform batch index so x loads become scalar (s_load)
    const int b = __builtin_amdgcn_readfirstlane((int)blockIdx.x * 4 + wid);

    // per-lane weight rows, resident in VGPRs
    float wih[Fn];
#pragma unroll
    for (int f4 = 0; f4 < Fn / 4; ++f4) {
        float4 v = *reinterpret_cast<const float4*>(Wih + lane * Fn + f4 * 4);
        wih[f4 * 4 + 0] = v.x; wih[f4 * 4 + 1] = v.y;
        wih[f4 * 4 + 2] = v.z; wih[f4 * 4 + 3] = v.w;
    }
    float whh[Hn];
#pragma unroll
    for (int k4 = 0; k4 < Hn / 4; ++k4) {
        float4 v = *reinterpret_cast<const float4*>(Whh + lane * Hn + k4 * 4);
        whh[k4 * 4 + 0] = v.x; whh[k4 * 4 + 1] = v.y;
        whh[k4 * 4 + 2] = v.z; whh[k4 * 4 + 3] = v.w;
    }
    const float bj = bih[lane] + bhh[lane];

    // gate-type select: group 2 (g-gate) uses tanh => act = 2*sigmoid(2z)-1
    const float mm   = ((lane >> 4) == 2) ? 2.0f : 1.0f;
    const float msub = mm - 1.0f;

    float c = 0.0f;
    float hs[Hn];   // broadcast hidden state (uniform -> SGPRs)
#pragma unroll
    for (int k = 0; k < Hn; ++k) hs[k] = 0.0f;

    const float* xrow = x + (size_t)b * (Tn * Fn);

    for (int t = 0; t < Tn; ++t) {
        float pre = bj;
        const float* xt = xrow + t * Fn;   // wave-uniform pointer
#pragma unroll
        for (int f4 = 0; f4 < Fn / 4; ++f4) {
            float4 xv = *reinterpret_cast<const float4*>(xt + f4 * 4);
            pre = fmaf(wih[f4 * 4 + 0], xv.x, pre);
            pre = fmaf(wih[f4 * 4 + 1], xv.y, pre);
            pre = fmaf(wih[f4 * 4 + 2], xv.z, pre);
            pre = fmaf(wih[f4 * 4 + 3], xv.w, pre);
        }
#pragma unroll
        for (int k = 0; k < Hn; ++k)
            pre = fmaf(whh[k], hs[k], pre);

        // act = sigmoid(pre) for i/f/o lanes, tanh(pre) for g lanes
        //   sigmoid: 1/(1+e^-z);  tanh: 2/(1+e^-2z) - 1
        float e   = __expf(-mm * pre);
        float act = fmaf(mm, __builtin_amdgcn_rcpf(1.0f + e), -msub);

        // gather f, g, o gates down to the i-lanes (0..15)
        float fg = __shfl_down(act, 16);
        float gg = __shfl_down(act, 32);
        float og = __shfl_down(act, 48);

        // lanes 0..15 hold valid c/h; other lanes compute garbage (unused)
        c = fmaf(fg, c, act * gg);
        float e2 = __expf(-2.0f * c);
        float th = fmaf(2.0f, __builtin_amdgcn_rcpf(1.0f + e2), -1.0f);
        float hnew = og * th;

        // broadcast h[0..15] to SGPRs for next step's recurrent dot
#pragma unroll
        for (int k = 0; k < Hn; ++k)
            hs[k] = __int_as_float(
                __builtin_amdgcn_readlane(__float_as_int(hnew), k));
    }

    if (lane == 0) {
        float po = bout[0];
#pragma unroll
        for (int k = 0; k < Hn; ++k)
            po = fmaf(hs[k], Wout[k], po);
        out[b] = __builtin_amdgcn_rcpf(1.0f + __expf(-po));
    }
}

extern "C" void kernel_launch(void* const* d_in, const int* in_sizes, int n_in,
                              void* d_out, int out_size, void* d_ws, size_t ws_size,
                              hipStream_t stream) {
    const float* x    = (const float*)d_in[0];
    const float* Wih  = (const float*)d_in[1];
    const float* Whh  = (const float*)d_in[2];
    const float* bih  = (const float*)d_in[3];
    const float* bhh  = (const float*)d_in[4];
    const float* Wout = (const float*)d_in[5];
    const float* bout = (const float*)d_in[6];
    float* out = (float*)d_out;

    lstm_fused<<<dim3(Bsz / 4), dim3(256), 0, stream>>>(
        x, Wih, Whh, bih, bhh, Wout, bout, out);
}

// Round 2
// 93.702 us; speedup vs baseline: 2.1955x; 2.1955x over previous
//
#include <hip/hip_runtime.h>

// Fused LSTM: B=4096, T=200, F=64, H=16, O=1.
// One wave per batch element. Input projection x@Wih^T done on the matrix
// pipe: per 16-timestep chunk, 8x mfma_f32_16x16x32_f16 -> 16x64 gx block,
// transposed to gate-major via per-wave LDS. Recurrence + activations on
// the VALU with gate->lane perm: lane 4k+{0,1,2,3} = unit k's {i,f,g,o},
// so gate gathers are quad-perm DPP movs instead of DS shuffles.

#define Bsz 4096
#define Tn  200
#define Fn  64
#define Hn  16

typedef _Float16 half8 __attribute__((ext_vector_type(8)));
typedef float    f32x4 __attribute__((ext_vector_type(4)));

// quad_perm DPP: lane (4q+i) reads lane (4q + sel_i); CTRL = sel0|sel1<<2|sel2<<4|sel3<<6
template <int CTRL>
__device__ __forceinline__ float quad_get(float v) {
    return __int_as_float(__builtin_amdgcn_update_dpp(
        0, __float_as_int(v), CTRL, 0xf, 0xf, true));
}

__device__ __forceinline__ half8 to_half8(const float4& a, const float4& b) {
    half8 h;
    h[0] = (_Float16)a.x; h[1] = (_Float16)a.y; h[2] = (_Float16)a.z; h[3] = (_Float16)a.w;
    h[4] = (_Float16)b.x; h[5] = (_Float16)b.y; h[6] = (_Float16)b.z; h[7] = (_Float16)b.w;
    return h;
}

__device__ __forceinline__ float rdl(float v, int srclane) {
    return __int_as_float(__builtin_amdgcn_readlane(__float_as_int(v), srclane));
}

// one LSTM timestep; gx = preactivation from MFMA (bias already folded in)
__device__ __forceinline__ void lstm_step(float gx, const float* whh, float* hs,
                                          float& c, float mm, float msub) {
    float pre = gx, p1 = 0.0f;
#pragma unroll
    for (int k = 0; k < 8; ++k) {
        pre = fmaf(whh[k],     hs[k],     pre);
        p1  = fmaf(whh[k + 8], hs[k + 8], p1);
    }
    pre += p1;
    // sigmoid for i/f/o (mm=1), tanh for g (mm=2): act = mm/(1+e^(-mm*z)) - (mm-1)
    float e   = __expf(-mm * pre);
    float act = fmaf(mm, __builtin_amdgcn_rcpf(1.0f + e), -msub);
    // unit k lives on lane 4k: pull f,g,o from lanes 4k+1,4k+2,4k+3
    float fg = quad_get<57>(act);    // rotate-by-1 within quad
    float gg = quad_get<78>(act);    // rotate-by-2
    float og = quad_get<147>(act);   // rotate-by-3
    c = fmaf(fg, c, act * gg);
    float e2 = __expf(-2.0f * c);
    float th = fmaf(2.0f, __builtin_amdgcn_rcpf(1.0f + e2), -1.0f);
    float hnew = og * th;
#pragma unroll
    for (int k = 0; k < 16; ++k)
        hs[k] = rdl(hnew, 4 * k);    // broadcast h to SGPRs
}

__global__ __launch_bounds__(256, 4) void lstm_fused(
    const float* __restrict__ x,     // [B, T, F]
    const float* __restrict__ Wih,   // [64, 64]
    const float* __restrict__ Whh,   // [64, 16]
    const float* __restrict__ bih,   // [64]
    const float* __restrict__ bhh,   // [64]
    const float* __restrict__ Wout,  // [1, 16]
    const float* __restrict__ bout,  // [1]
    float* __restrict__ out)         // [B, 1]
{
    const int lane = threadIdx.x & 63;
    const int wid  = threadIdx.x >> 6;
    const int b    = __builtin_amdgcn_readfirstlane((int)blockIdx.x * 4 + wid);

    // per-wave gx transpose buffer: [64 gates][16 trel], row stride 20 dwords
    __shared__ float xp_all[4][64 * 20];
    float* xp = &xp_all[wid][0];

    const int l15 = lane & 15;
    const int lhi = lane >> 4;
    const int g   = (lane & 3) * 16 + (lane >> 2);   // owned gate (perm)

    // ---- one-time: Wih^T fragments in fp16 (B operand) ----
    // frag[tl][kh]: lane holds col = tl*16+l15 (gate), k = kh*32 + lhi*8 + j
    half8 bfrag[4][2];
#pragma unroll
    for (int tl = 0; tl < 4; ++tl)
#pragma unroll
        for (int kh = 0; kh < 2; ++kh) {
            const float* wr = Wih + (tl * 16 + l15) * Fn + kh * 32 + lhi * 8;
            float4 w0 = *reinterpret_cast<const float4*>(wr);
            float4 w1 = *reinterpret_cast<const float4*>(wr + 4);
            bfrag[tl][kh] = to_half8(w0, w1);
        }

    float bsum[4];   // bias for gate tl*16+l15 (folded into MFMA C)
#pragma unroll
    for (int tl = 0; tl < 4; ++tl)
        bsum[tl] = bih[tl * 16 + l15] + bhh[tl * 16 + l15];

    float whh[Hn];   // Whh row of my gate (fp32, exact recurrence)
#pragma unroll
    for (int k4 = 0; k4 < 4; ++k4) {
        float4 v = *reinterpret_cast<const float4*>(Whh + g * Hn + k4 * 4);
        whh[k4 * 4 + 0] = v.x; whh[k4 * 4 + 1] = v.y;
        whh[k4 * 4 + 2] = v.z; whh[k4 * 4 + 3] = v.w;
    }

    const float mm   = ((lane & 3) == 2) ? 2.0f : 1.0f;   // g-gate -> tanh
    const float msub = mm - 1.0f;

    float c = 0.0f;
    float hs[Hn];
#pragma unroll
    for (int k = 0; k < Hn; ++k) hs[k] = 0.0f;

    const float* xb = x + (size_t)b * (Tn * Fn);

    // prefetched x chunk: lane reads row tc+l15, cols lhi*8 + {0..7, 32..39}
    float4 nx0, nx1, nx2, nx3;
    {
        const float* xr = xb + l15 * Fn + lhi * 8;
        nx0 = *reinterpret_cast<const float4*>(xr);
        nx1 = *reinterpret_cast<const float4*>(xr + 4);
        nx2 = *reinterpret_cast<const float4*>(xr + 32);
        nx3 = *reinterpret_cast<const float4*>(xr + 36);
    }

    // compute gx block for current chunk from nx*, transpose into LDS
    auto do_chunk = [&]() {
        half8 a0 = to_half8(nx0, nx1);   // A frag: row=l15, k = lhi*8+j
        half8 a1 = to_half8(nx2, nx3);   // k += 32
#pragma unroll
        for (int tl = 0; tl < 4; ++tl) {
            f32x4 acc = { bsum[tl], bsum[tl], bsum[tl], bsum[tl] };
            acc = __builtin_amdgcn_mfma_f32_16x16x32_f16(a0, bfrag[tl][0], acc, 0, 0, 0);
            acc = __builtin_amdgcn_mfma_f32_16x16x32_f16(a1, bfrag[tl][1], acc, 0, 0, 0);
            // D[row=lhi*4+r][col=l15] -> xp[gate*20 + trel]
            *reinterpret_cast<f32x4*>(&xp[(tl * 16 + l15) * 20 + lhi * 4]) = acc;
        }
    };

#pragma unroll 1
    for (int tc = 0; tc < Tn - 16; tc += 16) {   // 12 full chunks (t < 192)
        do_chunk();
        {   // prefetch next chunk (clamp rows past T-1; values unused)
            int trow = tc + 16 + l15;
            trow = trow > Tn - 1 ? Tn - 1 : trow;
            const float* xr = xb + trow * Fn + lhi * 8;
            nx0 = *reinterpret_cast<const float4*>(xr);
            nx1 = *reinterpret_cast<const float4*>(xr + 4);
            nx2 = *reinterpret_cast<const float4*>(xr + 32);
            nx3 = *reinterpret_cast<const float4*>(xr + 36);
        }
        const f32x4* qrow = reinterpret_cast<const f32x4*>(&xp[g * 20]);
        f32x4 q0 = qrow[0], q1 = qrow[1], q2 = qrow[2], q3 = qrow[3];
#pragma unroll
        for (int s = 0; s < 4; ++s) lstm_step(q0[s], whh, hs, c, mm, msub);
#pragma unroll
        for (int s = 0; s < 4; ++s) lstm_step(q1[s], whh, hs, c, mm, msub);
#pragma unroll
        for (int s = 0; s < 4; ++s) lstm_step(q2[s], whh, hs, c, mm, msub);
#pragma unroll
        for (int s = 0; s < 4; ++s) lstm_step(q3[s], whh, hs, c, mm, msub);
    }

    // tail chunk: t = 192..199 (8 steps; rows 200..207 were clamped garbage, unused)
    do_chunk();
    {
        const f32x4* qrow = reinterpret_cast<const f32x4*>(&xp[g * 20]);
        f32x4 q0 = qrow[0], q1 = qrow[1];
#pragma unroll
        for (int s = 0; s < 4; ++s) lstm_step(q0[s], whh, hs, c, mm, msub);
#pragma unroll
        for (int s = 0; s < 4; ++s) lstm_step(q1[s], whh, hs, c, mm, msub);
    }

    if (lane == 0) {
        float po = bout[0];
#pragma unroll
        for (int k = 0; k < Hn; ++k)
            po = fmaf(hs[k], Wout[k], po);
        out[b] = __builtin_amdgcn_rcpf(1.0f + __expf(-po));
    }
}

extern "C" void kernel_launch(void* const* d_in, const int* in_sizes, int n_in,
                              void* d_out, int out_size, void* d_ws, size_t ws_size,
                              hipStream_t stream) {
    const float* x    = (const float*)d_in[0];
    const float* Wih  = (const float*)d_in[1];
    const float* Whh  = (const float*)d_in[2];
    const float* bih  = (const float*)d_in[3];
    const float* bhh  = (const float*)d_in[4];
    const float* Wout = (const float*)d_in[5];
    const float* bout = (const float*)d_in[6];
    float* out = (float*)d_out;

    lstm_fused<<<dim3(Bsz / 4), dim3(256), 0, stream>>>(
        x, Wih, Whh, bih, bhh, Wout, bout, out);
}

// Round 3
// 85.159 us; speedup vs baseline: 2.4157x; 1.1003x over previous
//
#include <hip/hip_runtime.h>

// Fused LSTM: B=4096, T=200, F=64, H=16, O=1.
// TWO batch elements per wave (interleaved serial chains for ILP).
// Input projection x@Wih^T on the matrix pipe: per 16-step chunk,
// 2x(8x mfma_f32_16x16x32_f16) -> 16x64 gx blocks, transposed to
// gate-major via per-wave LDS. Recurrence + activations on the VALU
// with gate->lane perm: lane 4k+{0,1,2,3} = unit k's {i,f,g,o}, so
// gate gathers are quad-perm DPP movs.

#define Bsz 4096
#define Tn  200
#define Fn  64
#define Hn  16

typedef _Float16 half8 __attribute__((ext_vector_type(8)));
typedef float    f32x4 __attribute__((ext_vector_type(4)));

template <int CTRL>
__device__ __forceinline__ float quad_get(float v) {
    return __int_as_float(__builtin_amdgcn_update_dpp(
        0, __float_as_int(v), CTRL, 0xf, 0xf, true));
}

__device__ __forceinline__ half8 to_half8(const float4& a, const float4& b) {
    half8 h;
    h[0] = (_Float16)a.x; h[1] = (_Float16)a.y; h[2] = (_Float16)a.z; h[3] = (_Float16)a.w;
    h[4] = (_Float16)b.x; h[5] = (_Float16)b.y; h[6] = (_Float16)b.z; h[7] = (_Float16)b.w;
    return h;
}

__device__ __forceinline__ float rdl(float v, int srclane) {
    return __int_as_float(__builtin_amdgcn_readlane(__float_as_int(v), srclane));
}

// two interleaved LSTM timesteps (independent batches A,B)
__device__ __forceinline__ void lstm_step2(
    float gxA, float gxB, const float* whh,
    float* hsA, float* hsB, float& cA, float& cB,
    float mm, float cm, float msub)
{
    float pA = gxA, qA = 0.0f, pB = gxB, qB = 0.0f;
#pragma unroll
    for (int k = 0; k < 8; ++k) {
        pA = fmaf(whh[k],     hsA[k],     pA);
        pB = fmaf(whh[k],     hsB[k],     pB);
        qA = fmaf(whh[k + 8], hsA[k + 8], qA);
        qB = fmaf(whh[k + 8], hsB[k + 8], qB);
    }
    pA += qA; pB += qB;
    // sigmoid for i/f/o (mm=1), tanh for g (mm=2): act = mm/(1+2^(z*cm)) - msub
    float eA = __builtin_amdgcn_exp2f(pA * cm);
    float eB = __builtin_amdgcn_exp2f(pB * cm);
    float actA = fmaf(mm, __builtin_amdgcn_rcpf(1.0f + eA), -msub);
    float actB = fmaf(mm, __builtin_amdgcn_rcpf(1.0f + eB), -msub);
    // unit k on lane 4k: pull f,g,o from lanes 4k+1,4k+2,4k+3
    float fgA = quad_get<57>(actA),  fgB = quad_get<57>(actB);
    float ggA = quad_get<78>(actA),  ggB = quad_get<78>(actB);
    float ogA = quad_get<147>(actA), ogB = quad_get<147>(actB);
    cA = fmaf(fgA, cA, actA * ggA);
    cB = fmaf(fgB, cB, actB * ggB);
    // tanh(c) = 2/(1+2^(-2*log2e*c)) - 1
    float e2A = __builtin_amdgcn_exp2f(cA * -2.8853900817779268f);
    float e2B = __builtin_amdgcn_exp2f(cB * -2.8853900817779268f);
    float hnA = ogA * fmaf(2.0f, __builtin_amdgcn_rcpf(1.0f + e2A), -1.0f);
    float hnB = ogB * fmaf(2.0f, __builtin_amdgcn_rcpf(1.0f + e2B), -1.0f);
#pragma unroll
    for (int k = 0; k < 16; ++k) {
        hsA[k] = rdl(hnA, 4 * k);
        hsB[k] = rdl(hnB, 4 * k);
    }
}

__global__ __launch_bounds__(256, 2) void lstm_fused(
    const float* __restrict__ x,     // [B, T, F]
    const float* __restrict__ Wih,   // [64, 64]
    const float* __restrict__ Whh,   // [64, 16]
    const float* __restrict__ bih,   // [64]
    const float* __restrict__ bhh,   // [64]
    const float* __restrict__ Wout,  // [1, 16]
    const float* __restrict__ bout,  // [1]
    float* __restrict__ out)         // [B, 1]
{
    const int lane = threadIdx.x & 63;
    const int wid  = threadIdx.x >> 6;
    const int bA = __builtin_amdgcn_readfirstlane((int)blockIdx.x * 8 + wid * 2);
    const int bB = bA + 1;

    // per-wave, per-batch gx transpose buffer: [64 gates][16 t], stride 20
    __shared__ float xp_all[4][2][64 * 20];
    float* xpA = &xp_all[wid][0][0];
    float* xpB = &xp_all[wid][1][0];

    const int l15 = lane & 15;
    const int lhi = lane >> 4;
    const int g   = (lane & 3) * 16 + (lane >> 2);   // owned gate (perm)

    // ---- one-time: Wih^T fragments in fp16 (B operand) ----
    half8 bfrag[4][2];
#pragma unroll
    for (int tl = 0; tl < 4; ++tl)
#pragma unroll
        for (int kh = 0; kh < 2; ++kh) {
            const float* wr = Wih + (tl * 16 + l15) * Fn + kh * 32 + lhi * 8;
            float4 w0 = *reinterpret_cast<const float4*>(wr);
            float4 w1 = *reinterpret_cast<const float4*>(wr + 4);
            bfrag[tl][kh] = to_half8(w0, w1);
        }

    float bsum[4];
#pragma unroll
    for (int tl = 0; tl < 4; ++tl)
        bsum[tl] = bih[tl * 16 + l15] + bhh[tl * 16 + l15];

    float whh[Hn];   // Whh row of my gate (fp32, exact recurrence)
#pragma unroll
    for (int k4 = 0; k4 < 4; ++k4) {
        float4 v = *reinterpret_cast<const float4*>(Whh + g * Hn + k4 * 4);
        whh[k4 * 4 + 0] = v.x; whh[k4 * 4 + 1] = v.y;
        whh[k4 * 4 + 2] = v.z; whh[k4 * 4 + 3] = v.w;
    }

    const float mm   = ((lane & 3) == 2) ? 2.0f : 1.0f;   // g-gate -> tanh
    const float msub = mm - 1.0f;
    const float cm   = -mm * 1.4426950408889634f;         // exp2 scale

    float cA = 0.0f, cB = 0.0f;
    float hsA[Hn], hsB[Hn];
#pragma unroll
    for (int k = 0; k < Hn; ++k) { hsA[k] = 0.0f; hsB[k] = 0.0f; }

    const float* xbA = x + (size_t)bA * (Tn * Fn);
    const float* xbB = x + (size_t)bB * (Tn * Fn);

    // prefetched x chunks: lane reads row tc+l15, cols lhi*8 + {0..7,32..39}
    float4 nA0, nA1, nA2, nA3, nB0, nB1, nB2, nB3;
    {
        const float* xrA = xbA + l15 * Fn + lhi * 8;
        const float* xrB = xbB + l15 * Fn + lhi * 8;
        nA0 = *reinterpret_cast<const float4*>(xrA);
        nA1 = *reinterpret_cast<const float4*>(xrA + 4);
        nA2 = *reinterpret_cast<const float4*>(xrA + 32);
        nA3 = *reinterpret_cast<const float4*>(xrA + 36);
        nB0 = *reinterpret_cast<const float4*>(xrB);
        nB1 = *reinterpret_cast<const float4*>(xrB + 4);
        nB2 = *reinterpret_cast<const float4*>(xrB + 32);
        nB3 = *reinterpret_cast<const float4*>(xrB + 36);
    }

    auto do_chunk = [&](const float4& x0, const float4& x1,
                        const float4& x2, const float4& x3, float* xp) {
        half8 a0 = to_half8(x0, x1);   // A frag: row=l15, k=lhi*8+j
        half8 a1 = to_half8(x2, x3);   // k += 32
#pragma unroll
        for (int tl = 0; tl < 4; ++tl) {
            f32x4 acc = { bsum[tl], bsum[tl], bsum[tl], bsum[tl] };
            acc = __builtin_amdgcn_mfma_f32_16x16x32_f16(a0, bfrag[tl][0], acc, 0, 0, 0);
            acc = __builtin_amdgcn_mfma_f32_16x16x32_f16(a1, bfrag[tl][1], acc, 0, 0, 0);
            // D[row=lhi*4+r][col=l15] -> xp[gate*20 + trel]
            *reinterpret_cast<f32x4*>(&xp[(tl * 16 + l15) * 20 + lhi * 4]) = acc;
        }
    };

#pragma unroll 1
    for (int tc = 0; tc < Tn - 16; tc += 16) {   // 12 full chunks (t < 192)
        do_chunk(nA0, nA1, nA2, nA3, xpA);
        do_chunk(nB0, nB1, nB2, nB3, xpB);
        {   // prefetch next chunk (clamp rows past T-1; values unused)
            int trow = tc + 16 + l15;
            trow = trow > Tn - 1 ? Tn - 1 : trow;
            const float* xrA = xbA + trow * Fn + lhi * 8;
            const float* xrB = xbB + trow * Fn + lhi * 8;
            nA0 = *reinterpret_cast<const float4*>(xrA);
            nA1 = *reinterpret_cast<const float4*>(xrA + 4);
            nA2 = *reinterpret_cast<const float4*>(xrA + 32);
            nA3 = *reinterpret_cast<const float4*>(xrA + 36);
            nB0 = *reinterpret_cast<const float4*>(xrB);
            nB1 = *reinterpret_cast<const float4*>(xrB + 4);
            nB2 = *reinterpret_cast<const float4*>(xrB + 32);
            nB3 = *reinterpret_cast<const float4*>(xrB + 36);
        }
        const f32x4* qA = reinterpret_cast<const f32x4*>(&xpA[g * 20]);
        const f32x4* qB = reinterpret_cast<const f32x4*>(&xpB[g * 20]);
#pragma unroll
        for (int q = 0; q < 4; ++q) {
            f32x4 a = qA[q], b = qB[q];
#pragma unroll
            for (int s = 0; s < 4; ++s)
                lstm_step2(a[s], b[s], whh, hsA, hsB, cA, cB, mm, cm, msub);
        }
    }

    // tail: t = 192..199 (8 steps; clamped rows 200..207 unused)
    do_chunk(nA0, nA1, nA2, nA3, xpA);
    do_chunk(nB0, nB1, nB2, nB3, xpB);
    {
        const f32x4* qA = reinterpret_cast<const f32x4*>(&xpA[g * 20]);
        const f32x4* qB = reinterpret_cast<const f32x4*>(&xpB[g * 20]);
#pragma unroll
        for (int q = 0; q < 2; ++q) {
            f32x4 a = qA[q], b = qB[q];
#pragma unroll
            for (int s = 0; s < 4; ++s)
                lstm_step2(a[s], b[s], whh, hsA, hsB, cA, cB, mm, cm, msub);
        }
    }

    if (lane == 0) {
        float poA = bout[0], poB = bout[0];
#pragma unroll
        for (int k = 0; k < Hn; ++k) {
            poA = fmaf(hsA[k], Wout[k], poA);
            poB = fmaf(hsB[k], Wout[k], poB);
        }
        out[bA] = __builtin_amdgcn_rcpf(1.0f + __expf(-poA));
        out[bB] = __builtin_amdgcn_rcpf(1.0f + __expf(-poB));
    }
}

extern "C" void kernel_launch(void* const* d_in, const int* in_sizes, int n_in,
                              void* d_out, int out_size, void* d_ws, size_t ws_size,
                              hipStream_t stream) {
    const float* x    = (const float*)d_in[0];
    const float* Wih  = (const float*)d_in[1];
    const float* Whh  = (const float*)d_in[2];
    const float* bih  = (const float*)d_in[3];
    const float* bhh  = (const float*)d_in[4];
    const float* Wout = (const float*)d_in[5];
    const float* bout = (const float*)d_in[6];
    float* out = (float*)d_out;

    lstm_fused<<<dim3(Bsz / 8), dim3(256), 0, stream>>>(
        x, Wih, Whh, bih, bhh, Wout, bout, out);
}